// Round 5
// baseline (133.642 us; speedup 1.0000x reference)
//
#include <hip/hip_runtime.h>
#include <math.h>

#define DEV static __device__ __forceinline__

// ---- problem dims ----
constexpr int NB    = 16;
constexpr int BATCH = 32;
constexpr int DDIM  = 512;
constexpr int RK    = 64;
constexpr int LAY   = 5;                 // H-1
constexpr int MM    = 80;                // LAY*NB
constexpr int TLS   = NB * BATCH * DDIM; // 262144 (one T level)

constexpr float ETA_W   = 0.015f;
constexpr float LAM_C   = 0.65f, LAM_R = 0.35f;
constexpr float THETA0  = 0.5f;
constexpr float SPEC_MIN = 0.3f, SPEC_MAX = 4.0f;
constexpr float DW_CLIP = 5.0f;
constexpr float W_MAX   = 45.254833995939045f;     // sqrt(512)*2
constexpr float RSQ_D   = 0.044194173824159216f;   // 1/sqrt(512)

// ---- output layout (floats) ----
constexpr int OUT_MSE  = 0;
constexpr int OUT_EDGE = 1;                       // 1280
constexpr int OUT_A    = 1281;                    // 2621440
constexpr int OUT_B    = OUT_A + MM * DDIM * RK;  // 2622721
constexpr int OUT_T    = OUT_B + MM * DDIM * RK;  // 5244161

// ---- scratch parked inside OUT_B region (consumed by k_node before k_final) ----
constexpr int SCR_VIN  = 2622724;                 // 1310720 floats, 16B-aligned

// ---- ws layout (floats) ----
constexpr int WS_NORMB  = 0;        // 40960  per-(h,j,i,b) norms
constexpr int WS_TVN    = 40960;    // 32     per-b ||Tv||
constexpr int WS_TVM    = 41000;    // 512    mean_b Tv[b,d]
constexpr int WS_COEF   = 41600;    // 96     coef[l][i], l=0..5
constexpr int WS_SCALE  = 41700;    // 80
constexpr int WS_VM     = 42000;    // 40960  Vin_mean
constexpr int WS_P      = 83000;    // 5120   p[r] = Vin_mean . B col r
constexpr int WS_Q      = 88200;    // 5120   q[r] = gc . A col r
constexpr int WS_GC     = 93400;    // 40960  clipped g[d]

DEV float wave_reduce(float v) {
  #pragma unroll
  for (int o = 32; o > 0; o >>= 1) v += __shfl_down(v, o, 64);
  return v; // valid on lane 0
}

DEV float block_reduce_512(float v, float* sred) { // 512 thr, result on all
  v = wave_reduce(v);
  __syncthreads();
  if ((threadIdx.x & 63) == 0) sred[threadIdx.x >> 6] = v;
  __syncthreads();
  float s = 0.f;
  #pragma unroll
  for (int k = 0; k < 8; ++k) s += sred[k];
  return s;
}

DEV float bcast_lane(float v, int lane) {
  return __int_as_float(__builtin_amdgcn_readlane(__float_as_int(v), lane));
}

// ================ stage1: V_in sums + edge norms, mse, tvnorm, TVM ================
// blocks [0,2560): vin_norm; [2560,2592): tvnorm; 2592: mse; 2593: TVM
__global__ __launch_bounds__(256) void k_stage1(const float* __restrict__ V,
    const float* __restrict__ yh, const float* __restrict__ ys,
    float* __restrict__ out, float* __restrict__ ws) {
  __shared__ float sbuf[16][256];   // 16 KB (vin); small slices reused elsewhere
  int bid = blockIdx.x, t = threadIdx.x;
  if (bid < 2560) {
    // ---- V_in sums + per-edge norms ----
    int b = bid & 31, j = (bid >> 5) & 15, hh = bid >> 9;
    const float* base = V + (size_t)(((hh*16 + j)*16)*32 + b) * 512;
    float ax = 0.f, ay = 0.f;
    #pragma unroll
    for (int i = 0; i < 16; ++i) {
      float2 vv = ((const float2*)(base + (size_t)i * 16384))[t];
      sbuf[i][t] = vv.x*vv.x + vv.y*vv.y;
      ax += vv.x; ay += vv.y;
    }
    float2 o; o.x = ax; o.y = ay;
    ((float2*)(out + SCR_VIN + (size_t)((hh*16 + j)*32 + b) * 512))[t] = o;
    __syncthreads();
    int w = t >> 6, lane = t & 63;
    #pragma unroll
    for (int k = 0; k < 4; ++k) {
      int i = w * 4 + k;
      float s = sbuf[i][lane] + sbuf[i][lane+64] + sbuf[i][lane+128] + sbuf[i][lane+192];
      s = wave_reduce(s);
      if (lane == 0)
        ws[WS_NORMB + (size_t)((hh*16 + j)*16 + i) * 32 + b] = sqrtf(s);
    }
  } else if (bid < 2592) {
    // ---- per-batch ||Tv|| ----
    int b = bid - 2560;
    float2 a = ((const float2*)(yh + (size_t)b * 512))[t];
    float2 c = ((const float2*)(ys + (size_t)b * 512))[t];
    float d0 = c.x - a.x, d1 = c.y - a.y;
    float s = d0*d0 + d1*d1;
    s = wave_reduce(s);
    if ((t & 63) == 0) sbuf[0][t >> 6] = s;
    __syncthreads();
    if (t == 0)
      ws[WS_TVN + b] = sqrtf(sbuf[0][0]+sbuf[0][1]+sbuf[0][2]+sbuf[0][3]) * RSQ_D;
  } else if (bid == 2592) {
    // ---- mse ----
    float s = 0.f;
    for (int i = t; i < 4096; i += 256) {
      float4 a = ((const float4*)yh)[i], b = ((const float4*)ys)[i];
      float d0 = b.x-a.x, d1 = b.y-a.y, d2 = b.z-a.z, d3 = b.w-a.w;
      s += d0*d0 + d1*d1 + d2*d2 + d3*d3;
    }
    s = wave_reduce(s);
    if ((t & 63) == 0) sbuf[0][t >> 6] = s;
    __syncthreads();
    if (t == 0)
      out[OUT_MSE] = (sbuf[0][0]+sbuf[0][1]+sbuf[0][2]+sbuf[0][3]) * (1.f/16384.f);
  } else {
    // ---- TVM[d] = mean_b Tv[b,d] ----
    float s0 = 0.f, s1 = 0.f;
    #pragma unroll 4
    for (int b = 0; b < 32; ++b) {
      s0 += ys[b*512 + t]       - yh[b*512 + t];
      s1 += ys[b*512 + t + 256] - yh[b*512 + t + 256];
    }
    ws[WS_TVM + t]       = s0 * (RSQ_D / 32.f);
    ws[WS_TVM + t + 256] = s1 * (RSQ_D / 32.f);
  }
}

// ================ Gram (G=A^T A, H=B^T B in LDS) + power iteration fused ================
__global__ __launch_bounds__(256) void k_gp(const float* __restrict__ Aw,
                                            const float* __restrict__ Bww,
                                            float* __restrict__ ws) {
  __shared__ float tile[128 * 64];   // 32 KB
  __shared__ float GH[2][4096];      // 32 KB, symmetric 64x64 each
  __shared__ float y0s[4][64];
  int m = blockIdx.x;
  int t = threadIdx.x;
  int r1 = (t >> 4) * 4, r2 = (t & 15) * 4;
  const float* A1 = Aw  + (size_t)m * 32768;
  const float* B1 = Bww + (size_t)m * 32768;
  float acc[4][4];
  float y0acc = 0.f;

  // ---- side A: G + colsum(A) ----
  #pragma unroll
  for (int i = 0; i < 4; ++i)
    #pragma unroll
    for (int k = 0; k < 4; ++k) acc[i][k] = 0.f;
  for (int slice = 0; slice < 4; ++slice) {
    __syncthreads();
    const float* src = A1 + slice * 8192;
    #pragma unroll
    for (int k = 0; k < 8; ++k)
      ((float4*)tile)[t + k * 256] = ((const float4*)src)[t + k * 256];
    __syncthreads();
    {
      int rr = t & 63, q = t >> 6;
      float s = 0.f;
      #pragma unroll 8
      for (int dd = q*32; dd < q*32 + 32; ++dd) s += tile[dd*64 + rr];
      y0s[q][rr] = s;
    }
    __syncthreads();
    if (t < 64) y0acc += y0s[0][t] + y0s[1][t] + y0s[2][t] + y0s[3][t];
    #pragma unroll 4
    for (int dd = 0; dd < 128; ++dd) {
      float4 a1 = *(const float4*)&tile[dd*64 + r1];
      float4 a2 = *(const float4*)&tile[dd*64 + r2];
      float av[4] = {a1.x, a1.y, a1.z, a1.w};
      float bv[4] = {a2.x, a2.y, a2.z, a2.w};
      #pragma unroll
      for (int i = 0; i < 4; ++i)
        #pragma unroll
        for (int k = 0; k < 4; ++k) acc[i][k] += av[i] * bv[k];
    }
  }
  #pragma unroll
  for (int i = 0; i < 4; ++i)
    #pragma unroll
    for (int k = 0; k < 4; ++k) GH[0][(r1+i)*64 + r2+k] = acc[i][k];

  // ---- side B: H ----
  #pragma unroll
  for (int i = 0; i < 4; ++i)
    #pragma unroll
    for (int k = 0; k < 4; ++k) acc[i][k] = 0.f;
  for (int slice = 0; slice < 4; ++slice) {
    __syncthreads();
    const float* src = B1 + slice * 8192;
    #pragma unroll
    for (int k = 0; k < 8; ++k)
      ((float4*)tile)[t + k * 256] = ((const float4*)src)[t + k * 256];
    __syncthreads();
    #pragma unroll 4
    for (int dd = 0; dd < 128; ++dd) {
      float4 a1 = *(const float4*)&tile[dd*64 + r1];
      float4 a2 = *(const float4*)&tile[dd*64 + r2];
      float av[4] = {a1.x, a1.y, a1.z, a1.w};
      float bv[4] = {a2.x, a2.y, a2.z, a2.w};
      #pragma unroll
      for (int i = 0; i < 4; ++i)
        #pragma unroll
        for (int k = 0; k < 4; ++k) acc[i][k] += av[i] * bv[k];
    }
  }
  #pragma unroll
  for (int i = 0; i < 4; ++i)
    #pragma unroll
    for (int k = 0; k < 4; ++k) GH[1][(r1+i)*64 + r2+k] = acc[i][k];
  __syncthreads();

  // ---- power iteration on wave 0 (symmetric reads GH[c*64+r]: conflict-free) ----
  if (t < 64) {
    int r = t;
    float y = y0acc * RSQ_D;
    for (int it = 0; it < 20; ++it) {
      float z0=0.f, z1=0.f, z2=0.f, z3=0.f;
      #pragma unroll
      for (int c = 0; c < 16; ++c) {
        z0 = fmaf(GH[1][ c      *64 + r], bcast_lane(y, c),      z0);
        z1 = fmaf(GH[1][(c+16)*64 + r], bcast_lane(y, c+16),   z1);
        z2 = fmaf(GH[1][(c+32)*64 + r], bcast_lane(y, c+32),   z2);
        z3 = fmaf(GH[1][(c+48)*64 + r], bcast_lane(y, c+48),   z3);
      }
      float z = (z0+z1) + (z2+z3);
      float t0=0.f, t1=0.f, t2=0.f, t3=0.f;
      #pragma unroll
      for (int c = 0; c < 16; ++c) {
        t0 = fmaf(GH[0][ c      *64 + r], bcast_lane(z, c),      t0);
        t1 = fmaf(GH[0][(c+16)*64 + r], bcast_lane(z, c+16),   t1);
        t2 = fmaf(GH[0][(c+32)*64 + r], bcast_lane(z, c+32),   t2);
        t3 = fmaf(GH[0][(c+48)*64 + r], bcast_lane(z, c+48),   t3);
      }
      float tt = (t0+t1) + (t2+t3);
      float zt = z * tt;
      #pragma unroll
      for (int o = 32; o > 0; o >>= 1) zt += __shfl_xor(zt, o, 64);
      y = tt / (sqrtf(zt) + 1e-12f);
    }
    float z0=0.f, z1=0.f, z2=0.f, z3=0.f;
    #pragma unroll
    for (int c = 0; c < 16; ++c) {
      z0 = fmaf(GH[1][ c      *64 + r], bcast_lane(y, c),      z0);
      z1 = fmaf(GH[1][(c+16)*64 + r], bcast_lane(y, c+16),   z1);
      z2 = fmaf(GH[1][(c+32)*64 + r], bcast_lane(y, c+32),   z2);
      z3 = fmaf(GH[1][(c+48)*64 + r], bcast_lane(y, c+48),   z3);
    }
    float z = (z0+z1) + (z2+z3);
    float yz = y * z;
    #pragma unroll
    for (int o = 32; o > 0; o >>= 1) yz += __shfl_xor(yz, o, 64);
    if (r == 0)
      ws[WS_SCALE + m] = fminf(fmaxf(sqrtf(yz), SPEC_MIN), SPEC_MAX);
  }
}

// ================ coef (scale*w_blame) + chain + edge tensions ================
__global__ __launch_bounds__(256) void k_cc(float* __restrict__ ws,
                                            float* __restrict__ out) {
  __shared__ float C[5 * 256];
  __shared__ float coef[6 * 16];
  int t = threadIdx.x; // 256;  t = j*16+i
  int j = t >> 4;
  #pragma unroll
  for (int h = 0; h < 5; ++h) {
    const float* nb = ws + WS_NORMB + (size_t)(h * 256 + t) * 32;
    float n = 0.f;
    #pragma unroll 8
    for (int b = 0; b < 32; ++b) n += nb[b];
    n *= (1.f / 32.f);
    float s = n;
    s += __shfl_xor(s, 1, 64);
    s += __shfl_xor(s, 2, 64);
    s += __shfl_xor(s, 4, 64);
    s += __shfl_xor(s, 8, 64);
    C[h * 256 + t] = ws[WS_SCALE + h * 16 + j] * n / (s + 1e-9f);
  }
  if (t < 16) coef[5 * 16 + t] = (t == 0) ? 1.f : 0.f;
  __syncthreads();
  if (t < 16) {
    for (int h = 4; h >= 0; --h) {
      float s = 0.f;
      #pragma unroll
      for (int jj = 0; jj < 16; ++jj)
        s += C[h * 256 + jj * 16 + t] * coef[(h + 1) * 16 + jj];
      coef[h * 16 + t] = s;
    }
  }
  __syncthreads();
  float tvs = 0.f;
  #pragma unroll
  for (int b = 0; b < 32; ++b) tvs += ws[WS_TVN + b];
  float tvmean = tvs * (1.f / 32.f);
  #pragma unroll
  for (int h = 0; h < 5; ++h)
    out[OUT_EDGE + h * 256 + t] = C[h * 256 + t] * coef[(h + 1) * 16 + j] * tvmean;
  if (t < 96) ws[WS_COEF + t] = coef[t];
}

// ================ per-node stats: Yv, g, clip, p, q ================
constexpr int MTP = 516;  // LDS pitch for transposed 64x512 matrix
constexpr int YVP = 36;   // LDS pitch for YvT [64][32]

__global__ __launch_bounds__(512) void k_node(const float* __restrict__ Aw,
    const float* __restrict__ Bww, const float* out_all, float* __restrict__ ws) {
  __shared__ float MT[64 * MTP];   // 132.1 KB
  __shared__ float R2[4096];       // 16 KB
  __shared__ float gcol[512];
  __shared__ float sred[8];
  int m = blockIdx.x;
  int t = threadIdx.x;
  const float* A1  = Aw  + (size_t)m * 32768;
  const float* B1  = Bww + (size_t)m * 32768;
  const float* Vin = out_all + SCR_VIN + (size_t)m * 16384;
  int hh = m >> 4, j = m & 15;
  float coefval = ws[WS_COEF + (hh + 1) * 16 + j];

  auto stageT = [&](const float* src) {
    #pragma unroll
    for (int ch = 0; ch < 16; ++ch) {
      int g = ch * 2048 + t * 4;
      int d = g >> 6, r = g & 63;
      float4 v = *(const float4*)(src + g);
      MT[(r+0)*MTP + d] = v.x;
      MT[(r+1)*MTP + d] = v.y;
      MT[(r+2)*MTP + d] = v.z;
      MT[(r+3)*MTP + d] = v.w;
    }
  };

  stageT(B1);
  __syncthreads();

  // Yv[b][r] = sum_d Vin[b,d] * B1[d,r]
  {
    int rl = t & 31, bq = t >> 5;
    int b0 = bq * 2;
    float a00 = 0.f, a01 = 0.f, a10 = 0.f, a11 = 0.f;
    const float4* vp0 = (const float4*)(Vin + (size_t)b0 * 512);
    const float4* vp1 = (const float4*)(Vin + (size_t)(b0 + 1) * 512);
    #pragma unroll 4
    for (int d4 = 0; d4 < 128; ++d4) {
      float4 m0 = *(const float4*)&MT[rl * MTP + d4 * 4];
      float4 m1 = *(const float4*)&MT[(rl + 32) * MTP + d4 * 4];
      float4 v0 = vp0[d4];
      float4 v1 = vp1[d4];
      a00 += m0.x*v0.x + m0.y*v0.y + m0.z*v0.z + m0.w*v0.w;
      a01 += m0.x*v1.x + m0.y*v1.y + m0.z*v1.z + m0.w*v1.w;
      a10 += m1.x*v0.x + m1.y*v0.y + m1.z*v0.z + m1.w*v0.w;
      a11 += m1.x*v1.x + m1.y*v1.y + m1.z*v1.z + m1.w*v1.w;
    }
    R2[rl * YVP + b0]            = a00;
    R2[rl * YVP + b0 + 1]        = a01;
    R2[(rl + 32) * YVP + b0]     = a10;
    R2[(rl + 32) * YVP + b0 + 1] = a11;
  }
  __syncthreads();
  if (t < 64) {
    float s = 0.f;
    #pragma unroll 8
    for (int b = 0; b < 32; ++b) s += R2[t * YVP + b];
    ws[WS_P + m * 64 + t] = s * (1.f / 32.f);
  }
  float tmean, ssin, ssvm;
  {
    int d = t;
    float sv = 0.f, sq = 0.f;
    #pragma unroll 4
    for (int b = 0; b < 32; ++b) {
      float v = Vin[b * 512 + d];
      sv += v; sq += v * v;
    }
    float vmean = sv * (1.f / 32.f);
    tmean = coefval * ws[WS_TVM + d];
    ws[WS_VM + m * 512 + d] = vmean;
    ssin = block_reduce_512(sq, sred) * (1.f / 32.f);
    ssvm = block_reduce_512(vmean * vmean, sred);
  }
  __syncthreads();
  stageT(A1);
  __syncthreads();
  float gs = 0.f;
  float vga[4] = {0.f, 0.f, 0.f, 0.f}, fpa[4] = {0.f, 0.f, 0.f, 0.f};
  {
    int d4 = t >> 2, bg = t & 3;
    float acc[4][8];
    #pragma unroll
    for (int i = 0; i < 4; ++i)
      #pragma unroll
      for (int k = 0; k < 8; ++k) acc[i][k] = 0.f;
    #pragma unroll 2
    for (int rr = 0; rr < 64; ++rr) {
      float4 at = *(const float4*)&MT[rr * MTP + d4 * 4];
      float4 ya = *(const float4*)&R2[rr * YVP + bg * 8];
      float4 yb = *(const float4*)&R2[rr * YVP + bg * 8 + 4];
      float av[4] = {at.x, at.y, at.z, at.w};
      float yv[8] = {ya.x, ya.y, ya.z, ya.w, yb.x, yb.y, yb.z, yb.w};
      #pragma unroll
      for (int i = 0; i < 4; ++i)
        #pragma unroll
        for (int k = 0; k < 8; ++k) acc[i][k] += av[i] * yv[k];
    }
    #pragma unroll
    for (int i = 0; i < 4; ++i)
      #pragma unroll
      for (int k = 0; k < 8; ++k) {
        float vw = acc[i][k];
        float x = fminf(fmaxf(vw * 2.f, -40.f), 40.f);
        float e = __expf(x);
        float vo = (e - 1.f) / (e + 1.f);
        float fp = 1.f - vo * vo;
        gs += vo * vo;
        vga[i] += vo * fp;
        fpa[i] += fp;
      }
  }
  __syncthreads();
  {
    int d4 = t >> 2, bg = t & 3;
    #pragma unroll
    for (int i = 0; i < 4; ++i) {
      R2[bg * 512 + d4 * 4 + i] = vga[i];
      R2[2048 + bg * 512 + d4 * 4 + i] = fpa[i];
    }
  }
  float goodness = block_reduce_512(gs, sred) * (1.f / 32.f);
  float delta = goodness - THETA0 * (ssin + 1e-9f);
  {
    int d = t;
    float vg = R2[d] + R2[512 + d] + R2[1024 + d] + R2[1536 + d];
    float fp = R2[2048 + d] + R2[2048 + 512 + d] + R2[2048 + 1024 + d] + R2[2048 + 1536 + d];
    float g = LAM_C * delta * vg * (1.f / 32.f) + LAM_R * tmean * (fp * (1.f / 32.f));
    float gn2 = block_reduce_512(g * g, sred);
    float gnorm = sqrtf(gn2) * sqrtf(ssvm);
    float clipf = gnorm > DW_CLIP ? DW_CLIP / (gnorm + 1e-12f) : 1.f;
    float gcv = g * clipf;
    ws[WS_GC + m * 512 + d] = gcv;
    gcol[d] = gcv;
  }
  __syncthreads();
  {
    int r = t & 63, dq = t >> 6;
    float s = 0.f;
    #pragma unroll
    for (int k = 0; k < 16; ++k) {
      int d = dq * 64 + k * 4;
      float4 at = *(const float4*)&MT[r * MTP + d];
      float4 gv = *(const float4*)&gcol[d];
      s += at.x*gv.x + at.y*gv.y + at.z*gv.z + at.w*gv.w;
    }
    R2[dq * 64 + r] = s;
  }
  __syncthreads();
  if (t < 64) {
    float s = 0.f;
    #pragma unroll
    for (int p8 = 0; p8 < 8; ++p8) s += R2[p8 * 64 + t];
    ws[WS_Q + m * 64 + t] = s;
  }
}

// ================ final: T write + Adam update (float4 loads) ================
constexpr int TW_BLOCKS = 1536;   // 1536*256*4 = 1572864 T elements
constexpr int AD_HALF4  = 655360; // 2621440/4

__global__ __launch_bounds__(256) void k_final(const float* __restrict__ yh,
    const float* __restrict__ ys,
    const float* __restrict__ Aw, const float* __restrict__ Bww,
    const float* __restrict__ mA, const float* __restrict__ vA,
    const float* __restrict__ mB, const float* __restrict__ vB,
    const float* __restrict__ ws, float* __restrict__ out) {
  int bid = blockIdx.x, t = threadIdx.x;
  if (bid < TW_BLOCKS) {
    int g0 = (bid * 256 + t) * 4;
    int li = g0 >> 14;
    int bd = g0 & 16383;
    float4 a = *(const float4*)(yh + bd);
    float4 b = *(const float4*)(ys + bd);
    float cf = ws[WS_COEF + li] * RSQ_D;
    out[OUT_T + g0 + 0] = cf * (b.x - a.x);
    out[OUT_T + g0 + 1] = cf * (b.y - a.y);
    out[OUT_T + g0 + 2] = cf * (b.z - a.z);
    out[OUT_T + g0 + 3] = cf * (b.w - a.w);
    return;
  }
  int idx = (bid - TW_BLOCKS) * 256 + t;      // 0..1310719
  bool isB = idx >= AD_HALF4;
  int e = (isB ? idx - AD_HALF4 : idx) * 4;
  int m = e >> 15;
  int rem = e & 32767;
  int d = rem >> 6;
  int r = rem & 63;                            // multiple of 4
  float4 g4;
  const float *w0, *m0, *v0;
  int obase;
  if (!isB) {
    float gc = ws[WS_GC + m * 512 + d];
    float4 p = *(const float4*)&ws[WS_P + m * 64 + r];
    g4.x = gc * p.x; g4.y = gc * p.y; g4.z = gc * p.z; g4.w = gc * p.w;
    w0 = Aw; m0 = mA; v0 = vA; obase = OUT_A;
  } else {
    float vm = ws[WS_VM + m * 512 + d];
    float4 q = *(const float4*)&ws[WS_Q + m * 64 + r];
    g4.x = vm * q.x; g4.y = vm * q.y; g4.z = vm * q.z; g4.w = vm * q.w;
    w0 = Bww; m0 = mB; v0 = vB; obase = OUT_B;
  }
  float4 a4 = *(const float4*)&w0[e];
  float4 mm4 = *(const float4*)&m0[e];
  float4 vv4 = *(const float4*)&v0[e];
  float ga[4] = {g4.x, g4.y, g4.z, g4.w};
  float aa[4] = {a4.x, a4.y, a4.z, a4.w};
  float ma[4] = {mm4.x, mm4.y, mm4.z, mm4.w};
  float va[4] = {vv4.x, vv4.y, vv4.z, vv4.w};
  #pragma unroll
  for (int i = 0; i < 4; ++i) {
    float g = ga[i];
    float mn = 0.9f * ma[i] + 0.1f * g;
    float vn = 0.999f * va[i] + 0.001f * g * g;
    float u = aa[i] - ETA_W * (mn * 10.f) / (sqrtf(vn * 1000.f) + 1e-8f);
    u = fminf(fmaxf(u, -W_MAX), W_MAX);
    out[obase + e + i] = u;
  }
}

extern "C" void kernel_launch(void* const* d_in, const int* in_sizes, int n_in,
                              void* d_out, int out_size, void* d_ws, size_t ws_size,
                              hipStream_t stream) {
  (void)in_sizes; (void)n_in; (void)out_size; (void)ws_size;
  const float* Yh = (const float*)d_in[0];
  const float* Ys = (const float*)d_in[1];
  const float* V  = (const float*)d_in[2];
  const float* Aw = (const float*)d_in[3];
  const float* Bw = (const float*)d_in[4];
  const float* mA = (const float*)d_in[5];
  const float* vA = (const float*)d_in[6];
  const float* mB = (const float*)d_in[7];
  const float* vB = (const float*)d_in[8];
  float* out = (float*)d_out;
  float* ws  = (float*)d_ws;

  k_stage1<<<2594, 256, 0, stream>>>(V, Yh, Ys, out, ws);
  k_gp<<<80, 256, 0, stream>>>(Aw, Bw, ws);
  k_cc<<<1, 256, 0, stream>>>(ws, out);
  k_node<<<80, 512, 0, stream>>>(Aw, Bw, out, ws);
  k_final<<<TW_BLOCKS + 2 * (AD_HALF4 / 256), 256, 0, stream>>>(
      Yh, Ys, Aw, Bw, mA, vA, mB, vB, ws, out);
}

// Round 6
// 115.055 us; speedup vs baseline: 1.1615x; 1.1615x over previous
//
#include <hip/hip_runtime.h>
#include <math.h>

#define DEV static __device__ __forceinline__

// ---- problem dims ----
constexpr int NB    = 16;
constexpr int BATCH = 32;
constexpr int DDIM  = 512;
constexpr int RK    = 64;
constexpr int LAY   = 5;                 // H-1
constexpr int MM    = 80;                // LAY*NB
constexpr int TLS   = NB * BATCH * DDIM; // 262144 (one T level)

constexpr float ETA_W   = 0.015f;
constexpr float LAM_C   = 0.65f, LAM_R = 0.35f;
constexpr float THETA0  = 0.5f;
constexpr float SPEC_MIN = 0.3f, SPEC_MAX = 4.0f;
constexpr float DW_CLIP = 5.0f;
constexpr float W_MAX   = 45.254833995939045f;     // sqrt(512)*2
constexpr float RSQ_D   = 0.044194173824159216f;   // 1/sqrt(512)

// ---- output layout (floats) ----
constexpr int OUT_MSE  = 0;
constexpr int OUT_EDGE = 1;                       // 1280
constexpr int OUT_A    = 1281;                    // 2621440
constexpr int OUT_B    = OUT_A + MM * DDIM * RK;  // 2622721
constexpr int OUT_T    = OUT_B + MM * DDIM * RK;  // 5244161

// ---- scratch parked inside A/B output regions ----
// SCR_GP consumed by k_power before k_final writes OUT_A.
// SCR_VIN consumed by k_node before k_final writes OUT_B.
constexpr int SCR_GP   = 1284;                    // 160*4*4096 = 2621440 floats
constexpr int SCR_VIN  = SCR_GP + 2621440;        // 2622724 ; 1310720 floats

// ---- ws layout (floats) ----
constexpr int WS_NORMB  = 0;        // 40960  per-(h,j,i,b) norms
constexpr int WS_TVN    = 40960;    // 32     per-b ||Tv||
constexpr int WS_TVM    = 41000;    // 512    mean_b Tv[b,d] * RSQ_D
constexpr int WS_COEF   = 41600;    // 96     coef[l][i], l=0..5
constexpr int WS_SCALE  = 41700;    // 80
constexpr int WS_Y0P    = 41800;    // 20480  colsum partials of A
constexpr int WS_VM     = 62300;    // 40960  Vin_mean
constexpr int WS_P      = 103300;   // 5120   p[r] = Vin_mean . B col r
constexpr int WS_Q      = 108450;   // 5120   q[r] = gc . A col r
constexpr int WS_GC     = 113600;   // 40960  clipped g[d]

DEV float wave_reduce(float v) {
  #pragma unroll
  for (int o = 32; o > 0; o >>= 1) v += __shfl_down(v, o, 64);
  return v; // valid on lane 0
}

DEV float block_reduce_512(float v, float* sred) { // 512 thr, result on all
  v = wave_reduce(v);
  __syncthreads();
  if ((threadIdx.x & 63) == 0) sred[threadIdx.x >> 6] = v;
  __syncthreads();
  float s = 0.f;
  #pragma unroll
  for (int k = 0; k < 8; ++k) s += sred[k];
  return s;
}

DEV float bcast_lane(float v, int lane) {
  return __int_as_float(__builtin_amdgcn_readlane(__float_as_int(v), lane));
}

// ================ stage1: vin_norm | tvnorm | mse | TVM | gram ================
// blocks [0,2560): vin_norm; [2560,2592): tvnorm; 2592: mse; 2593: TVM;
// [2594, 2594+640): Gram partials (640 independent blocks, high occupancy).
__global__ __launch_bounds__(256) void k_stage1(const float* __restrict__ V,
    const float* __restrict__ yh, const float* __restrict__ ys,
    const float* __restrict__ Aw, const float* __restrict__ Bww,
    float* __restrict__ out, float* __restrict__ ws) {
  __shared__ float smem[8448];   // 33 KB union
  int bid = blockIdx.x, t = threadIdx.x;
  if (bid < 2560) {
    // ---- V_in sums + per-edge norms ----
    float (*sbuf)[256] = (float(*)[256])smem;    // 16 KB
    int b = bid & 31, j = (bid >> 5) & 15, hh = bid >> 9;
    const float* base = V + (size_t)(((hh*16 + j)*16)*32 + b) * 512;
    float ax = 0.f, ay = 0.f;
    #pragma unroll
    for (int i = 0; i < 16; ++i) {
      float2 vv = ((const float2*)(base + (size_t)i * 16384))[t];
      sbuf[i][t] = vv.x*vv.x + vv.y*vv.y;
      ax += vv.x; ay += vv.y;
    }
    float2 o; o.x = ax; o.y = ay;
    ((float2*)(out + SCR_VIN + (size_t)((hh*16 + j)*32 + b) * 512))[t] = o;
    __syncthreads();
    int w = t >> 6, lane = t & 63;
    #pragma unroll
    for (int k = 0; k < 4; ++k) {
      int i = w * 4 + k;
      float s = sbuf[i][lane] + sbuf[i][lane+64] + sbuf[i][lane+128] + sbuf[i][lane+192];
      s = wave_reduce(s);
      if (lane == 0)
        ws[WS_NORMB + (size_t)((hh*16 + j)*16 + i) * 32 + b] = sqrtf(s);
    }
  } else if (bid < 2592) {
    // ---- per-batch ||Tv|| ----
    int b = bid - 2560;
    float2 a = ((const float2*)(yh + (size_t)b * 512))[t];
    float2 c = ((const float2*)(ys + (size_t)b * 512))[t];
    float d0 = c.x - a.x, d1 = c.y - a.y;
    float s = d0*d0 + d1*d1;
    s = wave_reduce(s);
    if ((t & 63) == 0) smem[t >> 6] = s;
    __syncthreads();
    if (t == 0)
      ws[WS_TVN + b] = sqrtf(smem[0]+smem[1]+smem[2]+smem[3]) * RSQ_D;
  } else if (bid == 2592) {
    // ---- mse ----
    float s = 0.f;
    for (int i = t; i < 4096; i += 256) {
      float4 a = ((const float4*)yh)[i], b = ((const float4*)ys)[i];
      float d0 = b.x-a.x, d1 = b.y-a.y, d2 = b.z-a.z, d3 = b.w-a.w;
      s += d0*d0 + d1*d1 + d2*d2 + d3*d3;
    }
    s = wave_reduce(s);
    if ((t & 63) == 0) smem[t >> 6] = s;
    __syncthreads();
    if (t == 0)
      out[OUT_MSE] = (smem[0]+smem[1]+smem[2]+smem[3]) * (1.f/16384.f);
  } else if (bid == 2593) {
    // ---- TVM[d] = mean_b Tv[b,d] ----
    float s0 = 0.f, s1 = 0.f;
    #pragma unroll 4
    for (int b = 0; b < 32; ++b) {
      s0 += ys[b*512 + t]       - yh[b*512 + t];
      s1 += ys[b*512 + t + 256] - yh[b*512 + t + 256];
    }
    ws[WS_TVM + t]       = s0 * (RSQ_D / 32.f);
    ws[WS_TVM + t + 256] = s1 * (RSQ_D / 32.f);
  } else {
    // ---- Gram partials: G=A^T A, H=B^T B slices (+ colsum partials of A) ----
    float* tile = smem;                          // 128*64 floats = 32 KB
    float (*y0s)[64] = (float(*)[64])(smem + 8192);
    int bid0 = bid - 2594;                       // ((m*2+side)*4+slice)
    int slice = bid0 & 3, side = (bid0 >> 2) & 1, m = bid0 >> 3;
    const float* src = (side ? Bww : Aw) + (size_t)m * 32768 + slice * 8192;
    #pragma unroll
    for (int k = 0; k < 8; ++k)
      ((float4*)tile)[t + k * 256] = ((const float4*)src)[t + k * 256];
    __syncthreads();
    { // colsum partial
      int r = t & 63, q = t >> 6;
      float s = 0.f;
      #pragma unroll 8
      for (int dd = q * 32; dd < q * 32 + 32; ++dd) s += tile[dd * 64 + r];
      y0s[q][r] = s;
    }
    __syncthreads();
    if (side == 0 && t < 64)
      ws[WS_Y0P + (m * 4 + slice) * 64 + t] = y0s[0][t] + y0s[1][t] + y0s[2][t] + y0s[3][t];
    float acc[4][4];
    #pragma unroll
    for (int i = 0; i < 4; ++i)
      #pragma unroll
      for (int k = 0; k < 4; ++k) acc[i][k] = 0.f;
    int r1 = (t >> 4) * 4, r2 = (t & 15) * 4;
    #pragma unroll 4
    for (int dd = 0; dd < 128; ++dd) {
      float4 a1 = *(const float4*)&tile[dd * 64 + r1];
      float4 a2 = *(const float4*)&tile[dd * 64 + r2];
      float av[4] = {a1.x, a1.y, a1.z, a1.w};
      float bv[4] = {a2.x, a2.y, a2.z, a2.w};
      #pragma unroll
      for (int i = 0; i < 4; ++i)
        #pragma unroll
        for (int k = 0; k < 4; ++k) acc[i][k] += av[i] * bv[k];
    }
    float* outp = out + SCR_GP + (size_t)((m * 2 + side) * 4 + slice) * 4096;
    #pragma unroll
    for (int i = 0; i < 4; ++i) {
      float4 v; v.x = acc[i][0]; v.y = acc[i][1]; v.z = acc[i][2]; v.w = acc[i][3];
      *(float4*)&outp[(r1 + i) * 64 + r2] = v;
    }
  }
}

// ================ power iteration in 64-dim factor space (register-resident) ================
__global__ __launch_bounds__(64, 1) void k_power(const float* __restrict__ out,
                                                 float* __restrict__ ws) {
  int m = blockIdx.x;
  int r = threadIdx.x; // 64
  const float* gp = out + SCR_GP + (size_t)(m * 2 + 0) * 16384;
  const float* hp = out + SCR_GP + (size_t)(m * 2 + 1) * 16384;
  float Gc[64], Hc[64];
  #pragma unroll
  for (int c4 = 0; c4 < 16; ++c4) {
    const float* gb = gp + r * 64 + c4 * 4;
    float4 g0 = *(const float4*)(gb);
    float4 g1 = *(const float4*)(gb + 4096);
    float4 g2 = *(const float4*)(gb + 8192);
    float4 g3 = *(const float4*)(gb + 12288);
    Gc[c4*4+0] = g0.x+g1.x+g2.x+g3.x;
    Gc[c4*4+1] = g0.y+g1.y+g2.y+g3.y;
    Gc[c4*4+2] = g0.z+g1.z+g2.z+g3.z;
    Gc[c4*4+3] = g0.w+g1.w+g2.w+g3.w;
    const float* hb = hp + r * 64 + c4 * 4;
    float4 h0 = *(const float4*)(hb);
    float4 h1 = *(const float4*)(hb + 4096);
    float4 h2 = *(const float4*)(hb + 8192);
    float4 h3 = *(const float4*)(hb + 12288);
    Hc[c4*4+0] = h0.x+h1.x+h2.x+h3.x;
    Hc[c4*4+1] = h0.y+h1.y+h2.y+h3.y;
    Hc[c4*4+2] = h0.z+h1.z+h2.z+h3.z;
    Hc[c4*4+3] = h0.w+h1.w+h2.w+h3.w;
  }
  float y = (ws[WS_Y0P + (m*4+0)*64 + r] + ws[WS_Y0P + (m*4+1)*64 + r] +
             ws[WS_Y0P + (m*4+2)*64 + r] + ws[WS_Y0P + (m*4+3)*64 + r]) * RSQ_D;
  for (int it = 0; it < 20; ++it) {
    float z0 = 0.f, z1 = 0.f, z2 = 0.f, z3 = 0.f;
    #pragma unroll
    for (int c = 0; c < 16; ++c) {
      z0 = fmaf(Hc[c],      bcast_lane(y, c),      z0);
      z1 = fmaf(Hc[c + 16], bcast_lane(y, c + 16), z1);
      z2 = fmaf(Hc[c + 32], bcast_lane(y, c + 32), z2);
      z3 = fmaf(Hc[c + 48], bcast_lane(y, c + 48), z3);
    }
    float z = (z0 + z1) + (z2 + z3);
    float t0 = 0.f, t1 = 0.f, t2 = 0.f, t3 = 0.f;
    #pragma unroll
    for (int c = 0; c < 16; ++c) {
      t0 = fmaf(Gc[c],      bcast_lane(z, c),      t0);
      t1 = fmaf(Gc[c + 16], bcast_lane(z, c + 16), t1);
      t2 = fmaf(Gc[c + 32], bcast_lane(z, c + 32), t2);
      t3 = fmaf(Gc[c + 48], bcast_lane(z, c + 48), t3);
    }
    float tt = (t0 + t1) + (t2 + t3);
    float zt = z * tt;
    #pragma unroll
    for (int o = 32; o > 0; o >>= 1) zt += __shfl_xor(zt, o, 64);
    y = tt / (sqrtf(zt) + 1e-12f);
  }
  float z0 = 0.f, z1 = 0.f, z2 = 0.f, z3 = 0.f;
  #pragma unroll
  for (int c = 0; c < 16; ++c) {
    z0 = fmaf(Hc[c],      bcast_lane(y, c),      z0);
    z1 = fmaf(Hc[c + 16], bcast_lane(y, c + 16), z1);
    z2 = fmaf(Hc[c + 32], bcast_lane(y, c + 32), z2);
    z3 = fmaf(Hc[c + 48], bcast_lane(y, c + 48), z3);
  }
  float z = (z0 + z1) + (z2 + z3);
  float yz = y * z;
  #pragma unroll
  for (int o = 32; o > 0; o >>= 1) yz += __shfl_xor(yz, o, 64);
  if (r == 0)
    ws[WS_SCALE + m] = fminf(fmaxf(sqrtf(yz), SPEC_MIN), SPEC_MAX);
}

// ================ coef (scale*w_blame) + chain + edge tensions ================
__global__ __launch_bounds__(256) void k_cc(float* __restrict__ ws,
                                            float* __restrict__ out) {
  __shared__ float C[5 * 256];
  __shared__ float coef[6 * 16];
  int t = threadIdx.x; // 256;  t = j*16+i
  int j = t >> 4;
  #pragma unroll
  for (int h = 0; h < 5; ++h) {
    const float* nb = ws + WS_NORMB + (size_t)(h * 256 + t) * 32;
    float n = 0.f;
    #pragma unroll 8
    for (int b = 0; b < 32; ++b) n += nb[b];
    n *= (1.f / 32.f);
    float s = n;
    s += __shfl_xor(s, 1, 64);
    s += __shfl_xor(s, 2, 64);
    s += __shfl_xor(s, 4, 64);
    s += __shfl_xor(s, 8, 64);
    C[h * 256 + t] = ws[WS_SCALE + h * 16 + j] * n / (s + 1e-9f);
  }
  if (t < 16) coef[5 * 16 + t] = (t == 0) ? 1.f : 0.f;
  __syncthreads();
  if (t < 16) {
    for (int h = 4; h >= 0; --h) {
      float s = 0.f;
      #pragma unroll
      for (int jj = 0; jj < 16; ++jj)
        s += C[h * 256 + jj * 16 + t] * coef[(h + 1) * 16 + jj];
      coef[h * 16 + t] = s;
    }
  }
  __syncthreads();
  float tvs = 0.f;
  #pragma unroll
  for (int b = 0; b < 32; ++b) tvs += ws[WS_TVN + b];
  float tvmean = tvs * (1.f / 32.f);
  #pragma unroll
  for (int h = 0; h < 5; ++h)
    out[OUT_EDGE + h * 256 + t] = C[h * 256 + t] * coef[(h + 1) * 16 + j] * tvmean;
  if (t < 96) ws[WS_COEF + t] = coef[t];
}

// ================ per-node stats: Yv, g, clip, p, q ================
constexpr int MTP = 516;  // LDS pitch for transposed 64x512 matrix
constexpr int YVP = 36;   // LDS pitch for YvT [64][32]

__global__ __launch_bounds__(512) void k_node(const float* __restrict__ Aw,
    const float* __restrict__ Bww, const float* out_all, float* __restrict__ ws) {
  __shared__ float MT[64 * MTP];   // 132.1 KB
  __shared__ float R2[4096];       // 16 KB
  __shared__ float gcol[512];
  __shared__ float sred[8];
  int m = blockIdx.x;
  int t = threadIdx.x;
  const float* A1  = Aw  + (size_t)m * 32768;
  const float* B1  = Bww + (size_t)m * 32768;
  const float* Vin = out_all + SCR_VIN + (size_t)m * 16384;
  int hh = m >> 4, j = m & 15;
  float coefval = ws[WS_COEF + (hh + 1) * 16 + j];

  auto stageT = [&](const float* src) {
    #pragma unroll
    for (int ch = 0; ch < 16; ++ch) {
      int g = ch * 2048 + t * 4;
      int d = g >> 6, r = g & 63;
      float4 v = *(const float4*)(src + g);
      MT[(r+0)*MTP + d] = v.x;
      MT[(r+1)*MTP + d] = v.y;
      MT[(r+2)*MTP + d] = v.z;
      MT[(r+3)*MTP + d] = v.w;
    }
  };

  stageT(B1);
  __syncthreads();

  // Yv[b][r] = sum_d Vin[b,d] * B1[d,r]
  {
    int rl = t & 31, bq = t >> 5;
    int b0 = bq * 2;
    float a00 = 0.f, a01 = 0.f, a10 = 0.f, a11 = 0.f;
    const float4* vp0 = (const float4*)(Vin + (size_t)b0 * 512);
    const float4* vp1 = (const float4*)(Vin + (size_t)(b0 + 1) * 512);
    #pragma unroll 4
    for (int d4 = 0; d4 < 128; ++d4) {
      float4 m0 = *(const float4*)&MT[rl * MTP + d4 * 4];
      float4 m1 = *(const float4*)&MT[(rl + 32) * MTP + d4 * 4];
      float4 v0 = vp0[d4];
      float4 v1 = vp1[d4];
      a00 += m0.x*v0.x + m0.y*v0.y + m0.z*v0.z + m0.w*v0.w;
      a01 += m0.x*v1.x + m0.y*v1.y + m0.z*v1.z + m0.w*v1.w;
      a10 += m1.x*v0.x + m1.y*v0.y + m1.z*v0.z + m1.w*v0.w;
      a11 += m1.x*v1.x + m1.y*v1.y + m1.z*v1.z + m1.w*v1.w;
    }
    R2[rl * YVP + b0]            = a00;
    R2[rl * YVP + b0 + 1]        = a01;
    R2[(rl + 32) * YVP + b0]     = a10;
    R2[(rl + 32) * YVP + b0 + 1] = a11;
  }
  __syncthreads();
  if (t < 64) {
    float s = 0.f;
    #pragma unroll 8
    for (int b = 0; b < 32; ++b) s += R2[t * YVP + b];
    ws[WS_P + m * 64 + t] = s * (1.f / 32.f);
  }
  float tmean, ssin, ssvm;
  {
    int d = t;
    float sv = 0.f, sq = 0.f;
    #pragma unroll 4
    for (int b = 0; b < 32; ++b) {
      float v = Vin[b * 512 + d];
      sv += v; sq += v * v;
    }
    float vmean = sv * (1.f / 32.f);
    tmean = coefval * ws[WS_TVM + d];
    ws[WS_VM + m * 512 + d] = vmean;
    ssin = block_reduce_512(sq, sred) * (1.f / 32.f);
    ssvm = block_reduce_512(vmean * vmean, sred);
  }
  __syncthreads();
  stageT(A1);
  __syncthreads();
  float gs = 0.f;
  float vga[4] = {0.f, 0.f, 0.f, 0.f}, fpa[4] = {0.f, 0.f, 0.f, 0.f};
  {
    int d4 = t >> 2, bg = t & 3;
    float acc[4][8];
    #pragma unroll
    for (int i = 0; i < 4; ++i)
      #pragma unroll
      for (int k = 0; k < 8; ++k) acc[i][k] = 0.f;
    #pragma unroll 2
    for (int rr = 0; rr < 64; ++rr) {
      float4 at = *(const float4*)&MT[rr * MTP + d4 * 4];
      float4 ya = *(const float4*)&R2[rr * YVP + bg * 8];
      float4 yb = *(const float4*)&R2[rr * YVP + bg * 8 + 4];
      float av[4] = {at.x, at.y, at.z, at.w};
      float yv[8] = {ya.x, ya.y, ya.z, ya.w, yb.x, yb.y, yb.z, yb.w};
      #pragma unroll
      for (int i = 0; i < 4; ++i)
        #pragma unroll
        for (int k = 0; k < 8; ++k) acc[i][k] += av[i] * yv[k];
    }
    #pragma unroll
    for (int i = 0; i < 4; ++i)
      #pragma unroll
      for (int k = 0; k < 8; ++k) {
        float vw = acc[i][k];
        float x = fminf(fmaxf(vw * 2.f, -40.f), 40.f);
        float e = __expf(x);
        float vo = (e - 1.f) / (e + 1.f);
        float fp = 1.f - vo * vo;
        gs += vo * vo;
        vga[i] += vo * fp;
        fpa[i] += fp;
      }
  }
  __syncthreads();
  {
    int d4 = t >> 2, bg = t & 3;
    #pragma unroll
    for (int i = 0; i < 4; ++i) {
      R2[bg * 512 + d4 * 4 + i] = vga[i];
      R2[2048 + bg * 512 + d4 * 4 + i] = fpa[i];
    }
  }
  float goodness = block_reduce_512(gs, sred) * (1.f / 32.f);
  float delta = goodness - THETA0 * (ssin + 1e-9f);
  {
    int d = t;
    float vg = R2[d] + R2[512 + d] + R2[1024 + d] + R2[1536 + d];
    float fp = R2[2048 + d] + R2[2048 + 512 + d] + R2[2048 + 1024 + d] + R2[2048 + 1536 + d];
    float g = LAM_C * delta * vg * (1.f / 32.f) + LAM_R * tmean * (fp * (1.f / 32.f));
    float gn2 = block_reduce_512(g * g, sred);
    float gnorm = sqrtf(gn2) * sqrtf(ssvm);
    float clipf = gnorm > DW_CLIP ? DW_CLIP / (gnorm + 1e-12f) : 1.f;
    float gcv = g * clipf;
    ws[WS_GC + m * 512 + d] = gcv;
    gcol[d] = gcv;
  }
  __syncthreads();
  {
    int r = t & 63, dq = t >> 6;
    float s = 0.f;
    #pragma unroll
    for (int k = 0; k < 16; ++k) {
      int d = dq * 64 + k * 4;
      float4 at = *(const float4*)&MT[r * MTP + d];
      float4 gv = *(const float4*)&gcol[d];
      s += at.x*gv.x + at.y*gv.y + at.z*gv.z + at.w*gv.w;
    }
    R2[dq * 64 + r] = s;
  }
  __syncthreads();
  if (t < 64) {
    float s = 0.f;
    #pragma unroll
    for (int p8 = 0; p8 < 8; ++p8) s += R2[p8 * 64 + t];
    ws[WS_Q + m * 64 + t] = s;
  }
}

// ================ final: T write + Adam update (float4 loads) ================
constexpr int TW_BLOCKS = 1536;   // 1536*256*4 = 1572864 T elements
constexpr int AD_HALF4  = 655360; // 2621440/4

__global__ __launch_bounds__(256) void k_final(const float* __restrict__ yh,
    const float* __restrict__ ys,
    const float* __restrict__ Aw, const float* __restrict__ Bww,
    const float* __restrict__ mA, const float* __restrict__ vA,
    const float* __restrict__ mB, const float* __restrict__ vB,
    const float* __restrict__ ws, float* __restrict__ out) {
  int bid = blockIdx.x, t = threadIdx.x;
  if (bid < TW_BLOCKS) {
    int g0 = (bid * 256 + t) * 4;
    int li = g0 >> 14;
    int bd = g0 & 16383;
    float4 a = *(const float4*)(yh + bd);
    float4 b = *(const float4*)(ys + bd);
    float cf = ws[WS_COEF + li] * RSQ_D;
    out[OUT_T + g0 + 0] = cf * (b.x - a.x);
    out[OUT_T + g0 + 1] = cf * (b.y - a.y);
    out[OUT_T + g0 + 2] = cf * (b.z - a.z);
    out[OUT_T + g0 + 3] = cf * (b.w - a.w);
    return;
  }
  int idx = (bid - TW_BLOCKS) * 256 + t;      // 0..1310719
  bool isB = idx >= AD_HALF4;
  int e = (isB ? idx - AD_HALF4 : idx) * 4;
  int m = e >> 15;
  int rem = e & 32767;
  int d = rem >> 6;
  int r = rem & 63;                            // multiple of 4
  float4 g4;
  const float *w0, *m0, *v0;
  int obase;
  if (!isB) {
    float gc = ws[WS_GC + m * 512 + d];
    float4 p = *(const float4*)&ws[WS_P + m * 64 + r];
    g4.x = gc * p.x; g4.y = gc * p.y; g4.z = gc * p.z; g4.w = gc * p.w;
    w0 = Aw; m0 = mA; v0 = vA; obase = OUT_A;
  } else {
    float vm = ws[WS_VM + m * 512 + d];
    float4 q = *(const float4*)&ws[WS_Q + m * 64 + r];
    g4.x = vm * q.x; g4.y = vm * q.y; g4.z = vm * q.z; g4.w = vm * q.w;
    w0 = Bww; m0 = mB; v0 = vB; obase = OUT_B;
  }
  float4 a4 = *(const float4*)&w0[e];
  float4 mm4 = *(const float4*)&m0[e];
  float4 vv4 = *(const float4*)&v0[e];
  float ga[4] = {g4.x, g4.y, g4.z, g4.w};
  float aa[4] = {a4.x, a4.y, a4.z, a4.w};
  float ma[4] = {mm4.x, mm4.y, mm4.z, mm4.w};
  float va[4] = {vv4.x, vv4.y, vv4.z, vv4.w};
  #pragma unroll
  for (int i = 0; i < 4; ++i) {
    float g = ga[i];
    float mn = 0.9f * ma[i] + 0.1f * g;
    float vn = 0.999f * va[i] + 0.001f * g * g;
    float u = aa[i] - ETA_W * (mn * 10.f) / (sqrtf(vn * 1000.f) + 1e-8f);
    u = fminf(fmaxf(u, -W_MAX), W_MAX);
    out[obase + e + i] = u;
  }
}

extern "C" void kernel_launch(void* const* d_in, const int* in_sizes, int n_in,
                              void* d_out, int out_size, void* d_ws, size_t ws_size,
                              hipStream_t stream) {
  (void)in_sizes; (void)n_in; (void)out_size; (void)ws_size;
  const float* Yh = (const float*)d_in[0];
  const float* Ys = (const float*)d_in[1];
  const float* V  = (const float*)d_in[2];
  const float* Aw = (const float*)d_in[3];
  const float* Bw = (const float*)d_in[4];
  const float* mA = (const float*)d_in[5];
  const float* vA = (const float*)d_in[6];
  const float* mB = (const float*)d_in[7];
  const float* vB = (const float*)d_in[8];
  float* out = (float*)d_out;
  float* ws  = (float*)d_ws;

  k_stage1<<<2594 + 640, 256, 0, stream>>>(V, Yh, Ys, Aw, Bw, out, ws);
  k_power<<<80, 64, 0, stream>>>(out, ws);
  k_cc<<<1, 256, 0, stream>>>(ws, out);
  k_node<<<80, 512, 0, stream>>>(Aw, Bw, out, ws);
  k_final<<<TW_BLOCKS + 2 * (AD_HALF4 / 256), 256, 0, stream>>>(
      Yh, Ys, Aw, Bw, mA, vA, mB, vB, ws, out);
}